// Round 1
// baseline (885.025 us; speedup 1.0000x reference)
//
#include <hip/hip_runtime.h>
#include <hip/hip_bf16.h>

#define NN 100000
#define EE 1600000
#define RR 8
#define DD 64
#define SCAN_CHUNK 1024
#define NBLK ((NN + SCAN_CHUNK - 1) / SCAN_CHUNK)   // 98
#define BN_EPS 1e-5f

static __device__ __forceinline__ unsigned short f32_to_bf16(float f) {
    unsigned int u = __float_as_uint(f);
    unsigned int r = u + 0x7FFFu + ((u >> 16) & 1u);   // RNE
    return (unsigned short)(r >> 16);
}

// ---------------- CSR build ----------------

__global__ void k_count(const int* __restrict__ dst, int* __restrict__ deg) {
    int e = blockIdx.x * 256 + threadIdx.x;
    if (e < EE) atomicAdd(&deg[dst[e]], 1);
}

__global__ void k_scan1(const int* __restrict__ deg, int* __restrict__ part) {
    __shared__ int sdata[256];
    int t = threadIdx.x;
    int base = blockIdx.x * SCAN_CHUNK;
    int s = 0;
#pragma unroll
    for (int j = 0; j < 4; ++j) {
        int i = base + t * 4 + j;
        s += (i < NN) ? deg[i] : 0;
    }
    sdata[t] = s;
    __syncthreads();
    for (int off = 128; off > 0; off >>= 1) {
        if (t < off) sdata[t] += sdata[t + off];
        __syncthreads();
    }
    if (t == 0) part[blockIdx.x] = sdata[0];
}

__global__ void k_scan2(const int* __restrict__ part, int* __restrict__ pscan,
                        int* __restrict__ rowptr) {
    if (threadIdx.x == 0) {
        int run = 0;
        for (int i = 0; i < NBLK; ++i) { pscan[i] = run; run += part[i]; }
        rowptr[NN] = run;   // == EE
    }
}

__global__ void k_scan3(const int* __restrict__ deg, const int* __restrict__ pscan,
                        int* __restrict__ rowptr) {
    __shared__ int sdata[256];
    int t = threadIdx.x;
    int base = blockIdx.x * SCAN_CHUNK;
    int v[4];
    int s = 0;
#pragma unroll
    for (int j = 0; j < 4; ++j) {
        int i = base + t * 4 + j;
        v[j] = (i < NN) ? deg[i] : 0;
        s += v[j];
    }
    sdata[t] = s;
    __syncthreads();
    // Hillis-Steele inclusive scan over thread sums
    for (int off = 1; off < 256; off <<= 1) {
        int x = (t >= off) ? sdata[t - off] : 0;
        __syncthreads();
        sdata[t] += x;
        __syncthreads();
    }
    int run = pscan[blockIdx.x] + sdata[t] - s;   // exclusive prefix for this thread
#pragma unroll
    for (int j = 0; j < 4; ++j) {
        int i = base + t * 4 + j;
        if (i < NN) rowptr[i] = run;
        run += v[j];
    }
}

__global__ void k_fill(const int* __restrict__ src, const int* __restrict__ dst,
                       const int* __restrict__ et, int* __restrict__ cursor,
                       int* __restrict__ rec) {
    int e = blockIdx.x * 256 + threadIdx.x;
    if (e < EE) {
        int d = dst[e];
        int pos = atomicAdd(&cursor[d], 1);
        rec[pos] = (src[e] << 3) | et[e];
    }
}

// ---------------- per-(dst,rel) mean aggregation: one wave per dst ----------------

__global__ void k_agg(const float* __restrict__ X, const int* __restrict__ rowptr,
                      const int* __restrict__ rec, unsigned short* __restrict__ mean) {
    int wave = threadIdx.x >> 6;
    int lane = threadIdx.x & 63;
    int n = blockIdx.x * 4 + wave;
    if (n >= NN) return;
    int e0 = rowptr[n], e1 = rowptr[n + 1];
    float acc[RR];
    int cnt[RR];
#pragma unroll
    for (int k = 0; k < RR; ++k) { acc[k] = 0.f; cnt[k] = 0; }
    for (int e = e0; e < e1; ++e) {
        int rc = rec[e];
        int s = rc >> 3;
        int r = rc & 7;
        float v = X[s * DD + lane];
#pragma unroll
        for (int k = 0; k < RR; ++k) {
            if (r == k) { acc[k] += v; cnt[k] += 1; }
        }
    }
    size_t base = (size_t)n * (RR * DD);
#pragma unroll
    for (int k = 0; k < RR; ++k) {
        float c = (float)(cnt[k] > 1 ? cnt[k] : 1);
        float m = acc[k] / c;
        mean[base + k * DD + lane] = f32_to_bf16(m);
    }
}

// ---------------- fused GEMM: out = mean @ Wc + X @ root + bias ----------------
// mean: [N][512] bf16 ; Wc: [512][64] f32 ; X: [N][64] f32 ; root: [64][64] f32

#define LDSTRIDE 68   // pad 64 -> 68 floats: keeps ds_read_b128 16B-aligned, conflict-free

__global__ __launch_bounds__(256) void k_gemm(const unsigned short* __restrict__ meanB,
                                              const float* __restrict__ Xf,
                                              const float* __restrict__ W,
                                              const float* __restrict__ Root,
                                              const float* __restrict__ bias,
                                              float* __restrict__ Out) {
    __shared__ float a_s[64 * LDSTRIDE];
    __shared__ float w_s[64 * LDSTRIDE];
    int t = threadIdx.x;
    int n0 = blockIdx.x * 64;
    int tx = t & 15;        // -> cols 4*tx .. 4*tx+3
    int ty = t >> 4;        // -> rows 4*ty .. 4*ty+3
    int row_ld = t >> 2;    // staging row 0..63
    int kseg = (t & 3) * 16;

    float acc[4][4] = {};

    for (int c = 0; c < 9; ++c) {
        if (c < 8) {
            // stage A chunk (bf16 mean), transposed into a_s[k][row]
            unsigned short u[16];
            int n = n0 + row_ld;
            if (n < NN) {
                const uint4* p = (const uint4*)(meanB + (size_t)n * 512 + c * 64 + kseg);
                uint4 v0 = p[0];
                uint4 v1 = p[1];
                *(uint4*)&u[0] = v0;
                *(uint4*)&u[8] = v1;
            } else {
#pragma unroll
                for (int j = 0; j < 16; ++j) u[j] = 0;
            }
#pragma unroll
            for (int j = 0; j < 16; ++j) {
                a_s[(kseg + j) * LDSTRIDE + row_ld] =
                    __uint_as_float(((unsigned int)u[j]) << 16);
            }
            // stage W chunk
#pragma unroll
            for (int j = 0; j < 4; ++j) {
                float4 wv = *(const float4*)(W + (size_t)(c * 64 + row_ld) * 64 + kseg + j * 4);
                *(float4*)&w_s[row_ld * LDSTRIDE + kseg + j * 4] = wv;
            }
        } else {
            // root chunk: A = X tile (fp32), W = Root
            int n = n0 + row_ld;
#pragma unroll
            for (int j = 0; j < 4; ++j) {
                float4 v;
                if (n < NN) v = *(const float4*)(Xf + (size_t)n * 64 + kseg + j * 4);
                else v = make_float4(0.f, 0.f, 0.f, 0.f);
                a_s[(kseg + j * 4 + 0) * LDSTRIDE + row_ld] = v.x;
                a_s[(kseg + j * 4 + 1) * LDSTRIDE + row_ld] = v.y;
                a_s[(kseg + j * 4 + 2) * LDSTRIDE + row_ld] = v.z;
                a_s[(kseg + j * 4 + 3) * LDSTRIDE + row_ld] = v.w;
            }
#pragma unroll
            for (int j = 0; j < 4; ++j) {
                float4 wv = *(const float4*)(Root + (size_t)row_ld * 64 + kseg + j * 4);
                *(float4*)&w_s[row_ld * LDSTRIDE + kseg + j * 4] = wv;
            }
        }
        __syncthreads();
#pragma unroll 16
        for (int kk = 0; kk < 64; ++kk) {
            float4 av = *(const float4*)&a_s[kk * LDSTRIDE + 4 * ty];
            float4 bv = *(const float4*)&w_s[kk * LDSTRIDE + 4 * tx];
            acc[0][0] += av.x * bv.x; acc[0][1] += av.x * bv.y;
            acc[0][2] += av.x * bv.z; acc[0][3] += av.x * bv.w;
            acc[1][0] += av.y * bv.x; acc[1][1] += av.y * bv.y;
            acc[1][2] += av.y * bv.z; acc[1][3] += av.y * bv.w;
            acc[2][0] += av.z * bv.x; acc[2][1] += av.z * bv.y;
            acc[2][2] += av.z * bv.z; acc[2][3] += av.z * bv.w;
            acc[3][0] += av.w * bv.x; acc[3][1] += av.w * bv.y;
            acc[3][2] += av.w * bv.z; acc[3][3] += av.w * bv.w;
        }
        __syncthreads();
    }

    float4 bb = *(const float4*)(bias + 4 * tx);
#pragma unroll
    for (int i = 0; i < 4; ++i) {
        int n = n0 + 4 * ty + i;
        if (n < NN) {
            float4 o;
            o.x = acc[i][0] + bb.x;
            o.y = acc[i][1] + bb.y;
            o.z = acc[i][2] + bb.z;
            o.w = acc[i][3] + bb.w;
            *(float4*)(Out + (size_t)n * 64 + 4 * tx) = o;
        }
    }
}

// ---------------- BN column stats + BN+ReLU ----------------

__global__ void k_colstats(const float* __restrict__ H, float* __restrict__ stats) {
    int t = threadIdx.x;
    int col = t & 63;
    int rl = t >> 6;   // 0..3
    float s = 0.f, sq = 0.f;
    for (int n = blockIdx.x * 4 + rl; n < NN; n += gridDim.x * 4) {
        float v = H[(size_t)n * 64 + col];
        s += v;
        sq += v * v;
    }
    __shared__ float ss[256], sv[256];
    ss[t] = s; sv[t] = sq;
    __syncthreads();
    if (t < 128) { ss[t] += ss[t + 128]; sv[t] += sv[t + 128]; }
    __syncthreads();
    if (t < 64) {
        atomicAdd(&stats[col], ss[t] + ss[t + 64]);
        atomicAdd(&stats[64 + col], sv[t] + sv[t + 64]);
    }
}

__global__ void k_bnrelu(const float* __restrict__ H, const float* __restrict__ stats,
                         const float* __restrict__ gamma, const float* __restrict__ beta,
                         float* __restrict__ H2) {
    int idx = blockIdx.x * 256 + threadIdx.x;   // float4 index
    const int total = NN * DD / 4;
    if (idx >= total) return;
    int c0 = (idx & 15) * 4;
    float4 v = ((const float4*)H)[idx];
    float inv = 1.0f / (float)NN;
    float4 o;
    {
        float mu = stats[c0 + 0] * inv;
        float var = stats[64 + c0 + 0] * inv - mu * mu;
        float sc = gamma[c0 + 0] * rsqrtf(var + BN_EPS);
        float r = sc * (v.x - mu) + beta[c0 + 0];
        o.x = r > 0.f ? r : 0.f;
    }
    {
        float mu = stats[c0 + 1] * inv;
        float var = stats[64 + c0 + 1] * inv - mu * mu;
        float sc = gamma[c0 + 1] * rsqrtf(var + BN_EPS);
        float r = sc * (v.y - mu) + beta[c0 + 1];
        o.y = r > 0.f ? r : 0.f;
    }
    {
        float mu = stats[c0 + 2] * inv;
        float var = stats[64 + c0 + 2] * inv - mu * mu;
        float sc = gamma[c0 + 2] * rsqrtf(var + BN_EPS);
        float r = sc * (v.z - mu) + beta[c0 + 2];
        o.z = r > 0.f ? r : 0.f;
    }
    {
        float mu = stats[c0 + 3] * inv;
        float var = stats[64 + c0 + 3] * inv - mu * mu;
        float sc = gamma[c0 + 3] * rsqrtf(var + BN_EPS);
        float r = sc * (v.w - mu) + beta[c0 + 3];
        o.w = r > 0.f ? r : 0.f;
    }
    ((float4*)H2)[idx] = o;
}

// ---------------- launch ----------------

static inline size_t alignup(size_t x) { return (x + 255) & ~(size_t)255; }

extern "C" void kernel_launch(void* const* d_in, const int* in_sizes, int n_in,
                              void* d_out, int out_size, void* d_ws, size_t ws_size,
                              hipStream_t stream) {
    const float* x      = (const float*)d_in[0];
    const int*   eidx   = (const int*)d_in[1];     // [2][E]: src then dst
    const int*   etype  = (const int*)d_in[2];
    const float* w1     = (const float*)d_in[3];   // [8][64][64]
    const float* root1  = (const float*)d_in[4];
    const float* b1     = (const float*)d_in[5];
    const float* gamma1 = (const float*)d_in[6];
    const float* beta1  = (const float*)d_in[7];
    const float* w2     = (const float*)d_in[8];
    const float* root2  = (const float*)d_in[9];
    const float* b2     = (const float*)d_in[10];
    float* out = (float*)d_out;

    const int* src = eidx;
    const int* dst = eidx + EE;

    char* w = (char*)d_ws;
    int* deg    = (int*)w;            w += alignup((size_t)NN * 4);
    int* rowptr = (int*)w;            w += alignup((size_t)(NN + 1) * 4);
    int* cursor = (int*)w;            w += alignup((size_t)NN * 4);
    int* part   = (int*)w;            w += alignup(128 * 4);
    int* pscan  = (int*)w;            w += alignup(128 * 4);
    int* rec    = (int*)w;            w += alignup((size_t)EE * 4);
    unsigned short* mean = (unsigned short*)w; w += alignup((size_t)NN * RR * DD * 2);
    float* h    = (float*)w;          w += alignup((size_t)NN * DD * 4);
    float* h2   = (float*)w;          w += alignup((size_t)NN * DD * 4);
    float* stats = (float*)w;         w += alignup(128 * 4);

    // zero only what isn't fully overwritten
    hipMemsetAsync(deg, 0, (size_t)NN * 4, stream);
    hipMemsetAsync(stats, 0, 128 * 4, stream);

    // CSR build (shared by both layers)
    k_count<<<dim3(EE / 256), dim3(256), 0, stream>>>(dst, deg);
    k_scan1<<<dim3(NBLK), dim3(256), 0, stream>>>(deg, part);
    k_scan2<<<dim3(1), dim3(64), 0, stream>>>(part, pscan, rowptr);
    k_scan3<<<dim3(NBLK), dim3(256), 0, stream>>>(deg, pscan, rowptr);
    hipMemcpyAsync(cursor, rowptr, (size_t)NN * 4, hipMemcpyDeviceToDevice, stream);
    k_fill<<<dim3(EE / 256), dim3(256), 0, stream>>>(src, dst, etype, cursor, rec);

    // layer 1
    k_agg<<<dim3(NN / 4), dim3(256), 0, stream>>>(x, rowptr, rec, mean);
    k_gemm<<<dim3((NN + 63) / 64), dim3(256), 0, stream>>>(mean, x, w1, root1, b1, h);
    k_colstats<<<dim3(256), dim3(256), 0, stream>>>(h, stats);
    k_bnrelu<<<dim3(NN * DD / 4 / 256), dim3(256), 0, stream>>>(h, stats, gamma1, beta1, h2);

    // layer 2
    k_agg<<<dim3(NN / 4), dim3(256), 0, stream>>>(h2, rowptr, rec, mean);
    k_gemm<<<dim3((NN + 63) / 64), dim3(256), 0, stream>>>(mean, h2, w2, root2, b2, out);
}